// Round 14
// baseline (216.096 us; speedup 1.0000x reference)
//
#include <hip/hip_runtime.h>
#include <stdint.h>

#define SEQ 2048
#define BSZ 4
#define NH 16
#define HD 64
#define EMB 1024
#define NT (SEQ / 64)
#define QSCALE 0.1803368801111f   // 0.125 * log2(e)

using bf16x8 = __attribute__((ext_vector_type(8))) __bf16;
using u16x8  = __attribute__((ext_vector_type(8))) unsigned short;
using u32x4  = __attribute__((ext_vector_type(4))) uint32_t;
using f32x4  = __attribute__((ext_vector_type(4))) float;
using f32x16 = __attribute__((ext_vector_type(16))) float;

__device__ __forceinline__ float exp2v(float x) { return __builtin_amdgcn_exp2f(x); }

__device__ __forceinline__ unsigned short f2bf(float f) {
    union { float f; uint32_t u; } v; v.f = f;
    uint32_t r = v.u + 0x7fffu + ((v.u >> 16) & 1u);
    return (unsigned short)(r >> 16);
}

__device__ __forceinline__ uint32_t cvtpk(float lo, float hi) {
    uint32_t r;
    asm("v_cvt_pk_bf16_f32 %0, %1, %2" : "=v"(r) : "v"(lo), "v"(hi));
    return r;
}
__device__ __forceinline__ void plswap(uint32_t& a, uint32_t& b) {
    asm volatile("v_permlane32_swap_b32 %0, %1" : "+v"(a), "+v"(b));
}

// async global->LDS, 16B per lane; dest = wave-uniform base + lane*16
__device__ __forceinline__ void gload16(void* lds, const void* g) {
    __builtin_amdgcn_global_load_lds(
        (const __attribute__((address_space(1))) void*)g,
        (__attribute__((address_space(3))) void*)lds, 16, 0, 0);
}

// ---------------- cast fp32 -> bf16 ----------------
__global__ void cast_kernel(const float* __restrict__ s, unsigned short* __restrict__ d, int n) {
    int i = (blockIdx.x * blockDim.x + threadIdx.x) * 4;
    if (i + 3 >= n) {
        for (int j = 0; j < 4 && i + j < n; ++j) d[i + j] = f2bf(s[i + j]);
        return;
    }
    float4 v = *(const float4*)(s + i);
    ushort4 o;
    o.x = f2bf(v.x); o.y = f2bf(v.y); o.z = f2bf(v.z); o.w = f2bf(v.w);
    *(ushort4*)(d + i) = o;
}

// 4 weight matrices (1024x1024 each) in one launch; grid (1024, 4)
__global__ void cast4_kernel(const float* __restrict__ w0, const float* __restrict__ w1,
                             const float* __restrict__ w2, const float* __restrict__ w3,
                             unsigned short* __restrict__ d0, unsigned short* __restrict__ d1,
                             unsigned short* __restrict__ d2, unsigned short* __restrict__ d3) {
    const float* s; unsigned short* d;
    switch (blockIdx.y) {
        case 0:  s = w0; d = d0; break;
        case 1:  s = w1; d = d1; break;
        case 2:  s = w2; d = d2; break;
        default: s = w3; d = d3; break;
    }
    int i = (blockIdx.x * blockDim.x + threadIdx.x) * 4;
    float4 v = *(const float4*)(s + i);
    ushort4 o;
    o.x = f2bf(v.x); o.y = f2bf(v.y); o.z = f2bf(v.z); o.w = f2bf(v.w);
    *(ushort4*)(d + i) = o;
}

// ---------------- QKV GEMM: 8-phase 256x256 schedule (T2+T3+T4+T5) --------
// BM=BN=256, BK=64 (2 K-halves of 32), 16 K-steps, 8 waves (2M x 4N),
// per-wave C = 128x64. LDS 128KB: [2 dbuf][2 kh][256 rows][32 shorts],
// XOR-swizzled via pre-swizzled global source (chunk cg = cc ^ ((row>>1)&3)).
// Counted vmcnt(4) at phases 2 & 4 (never 0 in steady state): each drains
// exactly the K-half needed by the next two phases. Raw s_barrier.
// n-seg: cols 0-1023 -> Q (x QSCALE), 1024-2047 -> K, 2048-3071 -> V^T.
__global__ __launch_bounds__(512, 2)
void gemm_qkv_8ph(const unsigned short* __restrict__ A,
                  const unsigned short* __restrict__ Bw,
                  const float* __restrict__ b0, const float* __restrict__ b1,
                  const float* __restrict__ b2,
                  unsigned short* __restrict__ Cq, unsigned short* __restrict__ Ck,
                  unsigned short* __restrict__ CvT) {
    __shared__ __align__(16) unsigned char Asb[2][2][16384];  // [buf][kh][256r x 32c x 2B]
    __shared__ __align__(16) unsigned char Bsb[2][2][16384];

    const int t    = threadIdx.x;        // 0..511
    const int wid  = t >> 6;
    const int lane = t & 63;
    const int g    = lane >> 4;
    const int lr   = lane & 15;
    const int wm   = wid >> 2;           // 0..1 (row half)
    const int wn   = wid & 3;            // 0..3 (col quarter)
    const int m0   = blockIdx.x * 256;
    const int n0   = blockIdx.y * 256;

    // staging: call j stages LDS offset j*8192 + t*16 (linear);
    // row r = j*128 + (t>>2), lds chunk cc = t&3, source chunk cg = cc ^ ((r>>1)&3)
    const int r0 = t >> 2;
    const int cc = t & 3;

    auto stageA = [&](int buf, int kt, int kh) {
#pragma unroll
        for (int j = 0; j < 2; ++j) {
            int r  = j * 128 + r0;
            int cg = cc ^ ((r >> 1) & 3);
            gload16(&Asb[buf][kh][j * 8192 + wid * 1024],
                    A + (size_t)(m0 + r) * EMB + kt + kh * 32 + cg * 8);
        }
    };
    auto stageB = [&](int buf, int kt, int kh) {
#pragma unroll
        for (int j = 0; j < 2; ++j) {
            int r  = j * 128 + r0;
            int cg = cc ^ ((r >> 1) & 3);
            gload16(&Bsb[buf][kh][j * 8192 + wid * 1024],
                    Bw + (size_t)(n0 + r) * EMB + kt + kh * 32 + cg * 8);
        }
    };
    auto ldA = [&](int buf, int kh, int row) -> bf16x8 {
        int byte = row * 64 + ((g ^ ((row >> 1) & 3)) << 4);
        return *(const bf16x8*)(&Asb[buf][kh][byte]);
    };
    auto ldB = [&](int buf, int kh, int row) -> bf16x8 {
        int byte = row * 64 + ((g ^ ((row >> 1) & 3)) << 4);
        return *(const bf16x8*)(&Bsb[buf][kh][byte]);
    };

    // prologue: stage K-step 0 fully; drain h0 (leave h1's 4 loads in flight)
    stageA(0, 0, 0); stageB(0, 0, 0);
    stageA(0, 0, 1); stageB(0, 0, 1);

    f32x4 acc[8][4];
#pragma unroll
    for (int i = 0; i < 8; ++i)
#pragma unroll
        for (int j = 0; j < 4; ++j) acc[i][j] = (f32x4){0.f, 0.f, 0.f, 0.f};

    asm volatile("s_waitcnt vmcnt(4)" ::: "memory");
    __builtin_amdgcn_s_barrier();
    __builtin_amdgcn_sched_barrier(0);

#define MFMA_CLUSTER(MH)                                                              \
    do {                                                                              \
        __builtin_amdgcn_s_setprio(1);                                                \
        _Pragma("unroll")                                                             \
        for (int m = 0; m < 4; ++m) {                                                 \
            _Pragma("unroll")                                                         \
            for (int n = 0; n < 4; ++n)                                               \
                acc[(MH) * 4 + m][n] = __builtin_amdgcn_mfma_f32_16x16x32_bf16(       \
                    af[m], bfr[n], acc[(MH) * 4 + m][n], 0, 0, 0);                    \
        }                                                                             \
        __builtin_amdgcn_s_setprio(0);                                                \
    } while (0)

    for (int ts = 0; ts < 16; ++ts) {
        const int buf  = ts & 1;
        const int nbuf = buf ^ 1;
        const int ktn  = (ts + 1) * 64;
        const bool more = ts < 15;
        bf16x8 af[4], bfr[4];

        // ---- phase 1: kh=0, mh=0 ----
#pragma unroll
        for (int n = 0; n < 4; ++n) bfr[n] = ldB(buf, 0, wn * 64 + n * 16 + lr);
#pragma unroll
        for (int m = 0; m < 4; ++m) af[m] = ldA(buf, 0, wm * 128 + m * 16 + lr);
        if (more) stageA(nbuf, ktn, 0);
        __builtin_amdgcn_s_barrier();
        __builtin_amdgcn_sched_barrier(0);
        MFMA_CLUSTER(0);

        // ---- phase 2: kh=0, mh=1 ----
#pragma unroll
        for (int m = 0; m < 4; ++m) af[m] = ldA(buf, 0, wm * 128 + 64 + m * 16 + lr);
        if (more) {
            stageB(nbuf, ktn, 0);
            asm volatile("s_waitcnt vmcnt(4)" ::: "memory");   // lands h1(ts)
        } else {
            asm volatile("s_waitcnt vmcnt(0)" ::: "memory");
        }
        __builtin_amdgcn_s_barrier();
        __builtin_amdgcn_sched_barrier(0);
        MFMA_CLUSTER(1);

        // ---- phase 3: kh=1, mh=0 ----
#pragma unroll
        for (int n = 0; n < 4; ++n) bfr[n] = ldB(buf, 1, wn * 64 + n * 16 + lr);
#pragma unroll
        for (int m = 0; m < 4; ++m) af[m] = ldA(buf, 1, wm * 128 + m * 16 + lr);
        if (more) stageA(nbuf, ktn, 1);
        __builtin_amdgcn_s_barrier();
        __builtin_amdgcn_sched_barrier(0);
        MFMA_CLUSTER(0);

        // ---- phase 4: kh=1, mh=1 ----
#pragma unroll
        for (int m = 0; m < 4; ++m) af[m] = ldA(buf, 1, wm * 128 + 64 + m * 16 + lr);
        if (more) stageB(nbuf, ktn, 1);
        asm volatile("s_waitcnt vmcnt(4)" ::: "memory");        // lands h0(ts+1)
        __builtin_amdgcn_s_barrier();
        __builtin_amdgcn_sched_barrier(0);
        MFMA_CLUSTER(1);
    }
#undef MFMA_CLUSTER

    // epilogue: per n-tile segment routing (tiles never straddle 1024 cols)
#pragma unroll
    for (int n = 0; n < 4; ++n) {
        int colG = n0 + wn * 64 + n * 16 + lr;
        int seg  = colG >> 10;
        int colL = colG & 1023;
        const float* bias = seg == 0 ? b0 : (seg == 1 ? b1 : b2);
        float bv  = bias[colL];
        float scl = seg == 0 ? QSCALE : 1.0f;
#pragma unroll
        for (int mq = 0; mq < 8; ++mq) {
            int rowg = m0 + wm * 128 + mq * 16 + g * 4;
            if (seg == 2) {
                int bb = rowg >> 11, seq = rowg & 2047;
                ushort4 w;
                w.x = f2bf(acc[mq][n][0] + bv);
                w.y = f2bf(acc[mq][n][1] + bv);
                w.z = f2bf(acc[mq][n][2] + bv);
                w.w = f2bf(acc[mq][n][3] + bv);
                *(ushort4*)(CvT + ((size_t)(bb * 1024 + colL)) * SEQ + seq) = w;
            } else {
                unsigned short* Cw = seg == 0 ? Cq : Ck;
#pragma unroll
                for (int rr = 0; rr < 4; ++rr)
                    Cw[(size_t)(rowg + rr) * EMB + colL] = f2bf((acc[mq][n][rr] + bv) * scl);
            }
        }
    }
}

// ---------------- GEMM (m97 structure, proven) — out-projection ------------
template <int MODE>
__global__ __launch_bounds__(256, 2)
void gemm_bt(const unsigned short* __restrict__ A,
             const unsigned short* __restrict__ Bw,
             const float* __restrict__ b0,
             void* __restrict__ C0,
             int M, int N, int Kd) {
    __shared__ unsigned short As[128][64];
    __shared__ unsigned short Bs[128][64];

    const int t    = threadIdx.x;
    const int lane = t & 63;
    const int wid  = t >> 6;
    const int g    = lane >> 4;
    const int lr   = lane & 15;
    const int wm   = wid >> 1, wn = wid & 1;
    const int m0   = blockIdx.x * 128, n0 = blockIdx.y * 128;
    const int srow = lane >> 3;
    const int scol = (lane & 7) * 8;

    f32x4 acc[4][4];
    const f32x4 zero = {0.f, 0.f, 0.f, 0.f};
#pragma unroll
    for (int i = 0; i < 4; ++i)
#pragma unroll
        for (int j = 0; j < 4; ++j) acc[i][j] = zero;

    for (int kt = 0; kt < Kd; kt += 64) {
#pragma unroll
        for (int p = 0; p < 4; ++p) {
            int rowA = wid * 32 + p * 8;
            gload16(&As[rowA][0], A  + (size_t)(m0 + rowA + srow) * Kd + kt + scol);
            gload16(&Bs[rowA][0], Bw + (size_t)(n0 + rowA + srow) * Kd + kt + scol);
        }
        __syncthreads();
#pragma unroll
        for (int ks = 0; ks < 2; ++ks) {
            bf16x8 af[4], bfr[4];
#pragma unroll
            for (int m = 0; m < 4; ++m)
                af[m] = *(const bf16x8*)&As[wm * 64 + m * 16 + lr][ks * 32 + g * 8];
#pragma unroll
            for (int n = 0; n < 4; ++n)
                bfr[n] = *(const bf16x8*)&Bs[wn * 64 + n * 16 + lr][ks * 32 + g * 8];
#pragma unroll
            for (int m = 0; m < 4; ++m)
#pragma unroll
                for (int n = 0; n < 4; ++n)
                    acc[m][n] = __builtin_amdgcn_mfma_f32_16x16x32_bf16(af[m], bfr[n], acc[m][n], 0, 0, 0);
        }
        __syncthreads();
    }

#pragma unroll
    for (int n = 0; n < 4; ++n) {
        int colg = n0 + wn * 64 + n * 16 + lr;
        float bv = b0[colg];
#pragma unroll
        for (int m = 0; m < 4; ++m) {
            int rowg = m0 + wm * 64 + m * 16 + g * 4;
#pragma unroll
            for (int r = 0; r < 4; ++r)
                ((float*)C0)[(size_t)(rowg + r) * N + colg] = acc[m][n][r] + bv;
        }
    }
}

// ---------------- Flash attention v8 (round-8 proven, best: 94.2 us) -------
__global__ __launch_bounds__(512, 4)
void flash_attn(const unsigned short* __restrict__ Q,
                const unsigned short* __restrict__ K,
                const unsigned short* __restrict__ VT,
                unsigned short* __restrict__ O) {
    __shared__ unsigned char KsB[2][64 * 128];
    __shared__ unsigned char VtB[2][64 * 128];

    const int nwg  = gridDim.x * gridDim.y * gridDim.z;
    const int cpx  = nwg >> 3;
    const int bid0 = (blockIdx.z * gridDim.y + blockIdx.y) * gridDim.x + blockIdx.x;
    const int bid  = (bid0 % 8) * cpx + (bid0 / 8);
    const int bx   = bid & (gridDim.x - 1);
    const int h    = (bid >> 3) & 15;
    const int b    = bid >> 7;

    const int t    = threadIdx.x;
    const int wid  = t >> 6;
    const int lane = t & 63;
    const int l31  = lane & 31;
    const int hi   = lane >> 5;
    const int hi16 = hi << 4;
    const int sw   = (l31 & 7) << 4;
    const int qbase = bx * 256 + wid * 32;
    const size_t rowbase = (size_t)b * SEQ;
    const unsigned short* Kh  = K + rowbase * EMB + h * HD;
    const unsigned short* Vth = VT + (size_t)(b * 1024 + h * HD) * SEQ;

    const int grow = t >> 3;
    const int gc16 = (t & 7) ^ (grow & 7);
    const unsigned short* Ksrc0 = Kh  + (size_t)grow * EMB + gc16 * 8;
    const unsigned short* Vsrc0 = Vth + (size_t)grow * SEQ + gc16 * 8;

    bf16x8 qf[4];
#pragma unroll
    for (int db = 0; db < 4; ++db)
        qf[db] = *(const bf16x8*)(Q + (rowbase + qbase + l31) * EMB + h * HD + db * 16 + hi * 8);

    bf16x8 vones;
#pragma unroll
    for (int j = 0; j < 8; ++j) vones[j] = (__bf16)1.0f;

    f32x16 o0, o1, o2;
#pragma unroll
    for (int r = 0; r < 16; ++r) { o0[r] = 0.f; o1[r] = 0.f; o2[r] = 0.f; }
    float me = -1e30f;

    auto issue_tile = [&](int kt) {
        unsigned char* Ks = KsB[kt & 1] + wid * 1024;
        unsigned char* Vt = VtB[kt & 1] + wid * 1024;
        gload16(Ks, Ksrc0 + (size_t)kt * 64 * EMB);
        gload16(Vt, Vsrc0 + kt * 64);
    };
    issue_tile(0);

    for (int kt = 0; kt < NT; ++kt) {
        unsigned char* Ks = KsB[kt & 1];
        unsigned char* Vt = VtB[kt & 1];

        __syncthreads();

        if (kt + 1 < NT) issue_tile(kt + 1);

        f32x16 s0, s1;
#pragma unroll
        for (int r = 0; r < 16; ++r) { s0[r] = 0.f; s1[r] = 0.f; }
        __builtin_amdgcn_s_setprio(1);
#pragma unroll
        for (int db = 0; db < 4; ++db) {
            bf16x8 kf0 = *(const bf16x8*)(Ks + l31 * 128        + ((db * 32 + hi16) ^ sw));
            bf16x8 kf1 = *(const bf16x8*)(Ks + (l31 + 32) * 128 + ((db * 32 + hi16) ^ sw));
            s0 = __builtin_amdgcn_mfma_f32_32x32x16_bf16(kf0, qf[db], s0, 0, 0, 0);
            s1 = __builtin_amdgcn_mfma_f32_32x32x16_bf16(kf1, qf[db], s1, 0, 0, 0);
        }
        __builtin_amdgcn_s_setprio(0);

        float pm = fmaxf(fmaxf(s0[0], s0[1]), s0[2]);
#pragma unroll
        for (int r = 3; r < 15; r += 2) pm = fmaxf(fmaxf(pm, s0[r]), s0[r + 1]);
        pm = fmaxf(pm, s0[15]);
#pragma unroll
        for (int r = 0; r < 16; r += 2) pm = fmaxf(fmaxf(pm, s1[r]), s1[r + 1]);
        pm = fmaxf(pm, __shfl_xor(pm, 32));

        if (!__all(pm - me <= 8.0f)) {
            float mn = fmaxf(me, pm);
            float al = exp2v(me - mn);
            me = mn;
#pragma unroll
            for (int r = 0; r < 16; ++r) {
                int addr = hi16 + (((r & 3) + 8 * (r >> 2)) << 2);
                float ar = __int_as_float(
                    __builtin_amdgcn_ds_bpermute(addr, __float_as_int(al)));
                o0[r] *= ar; o1[r] *= ar; o2[r] *= ar;
            }
        }

        s0 = s0 - me;
        s1 = s1 - me;
#pragma unroll
        for (int r = 0; r < 16; ++r) s0[r] = exp2v(s0[r]);
#pragma unroll
        for (int r = 0; r < 16; ++r) s1[r] = exp2v(s1[r]);

        bf16x8 pa[4];
#pragma unroll
        for (int kb = 0; kb < 2; ++kb) {
            uint32_t dw[8];
#pragma unroll
            for (int i = 0; i < 8; ++i)
                dw[i] = kb == 0 ? cvtpk(s0[2 * i], s0[2 * i + 1])
                                : cvtpk(s1[2 * i], s1[2 * i + 1]);
            plswap(dw[0], dw[2]); plswap(dw[1], dw[3]);
            plswap(dw[4], dw[6]); plswap(dw[5], dw[7]);
            u32x4 w0 = {dw[0], dw[1], dw[2], dw[3]};
            u32x4 w1 = {dw[4], dw[5], dw[6], dw[7]};
            pa[kb * 2]     = __builtin_bit_cast(bf16x8, w0);
            pa[kb * 2 + 1] = __builtin_bit_cast(bf16x8, w1);
        }

        __builtin_amdgcn_s_setprio(1);
#pragma unroll
        for (int kk = 0; kk < 4; ++kk) {
            bf16x8 vf0 = *(const bf16x8*)(Vt + l31 * 128        + ((kk * 32 + hi16) ^ sw));
            bf16x8 vf1 = *(const bf16x8*)(Vt + (l31 + 32) * 128 + ((kk * 32 + hi16) ^ sw));
            o0 = __builtin_amdgcn_mfma_f32_32x32x16_bf16(pa[kk], vf0, o0, 0, 0, 0);
            o1 = __builtin_amdgcn_mfma_f32_32x32x16_bf16(pa[kk], vf1, o1, 0, 0, 0);
            o2 = __builtin_amdgcn_mfma_f32_32x32x16_bf16(pa[kk], vones, o2, 0, 0, 0);
        }
        __builtin_amdgcn_s_setprio(0);
    }

#pragma unroll
    for (int r = 0; r < 16; ++r) {
        float inv = 1.0f / o2[r];
        int q = qbase + (r & 3) + 8 * (r >> 2) + 4 * hi;
        size_t ro = (rowbase + q) * EMB + h * HD;
        O[ro + l31]      = f2bf(o0[r] * inv);
        O[ro + 32 + l31] = f2bf(o1[r] * inv);
    }
}

extern "C" void kernel_launch(void* const* d_in, const int* in_sizes, int n_in,
                              void* d_out, int out_size, void* d_ws, size_t ws_size,
                              hipStream_t stream) {
    const float* x  = (const float*)d_in[0];
    const float* wq = (const float*)d_in[1];
    const float* bq = (const float*)d_in[2];
    const float* wk = (const float*)d_in[3];
    const float* bk = (const float*)d_in[4];
    const float* wv = (const float*)d_in[5];
    const float* bv = (const float*)d_in[6];
    const float* wo = (const float*)d_in[7];
    const float* bo = (const float*)d_in[8];

    char* ws = (char*)d_ws;
    const size_t M = (size_t)BSZ * SEQ;              // 8192
    unsigned short* xb    = (unsigned short*)ws;                       // 16 MB, reused as attn out
    unsigned short* wqkvb = (unsigned short*)(ws + (size_t)16 * 1024 * 1024);  // 6 MB
    unsigned short* wob   = (unsigned short*)(ws + (size_t)22 * 1024 * 1024);  // 2 MB
    unsigned short* Qb    = (unsigned short*)(ws + (size_t)24 * 1024 * 1024);
    unsigned short* Kb    = Qb + M * EMB;
    unsigned short* VTb   = Kb + M * EMB;            // V^T [b*16+h][64][2048]

    const int nX = (int)(M * EMB);
    cast_kernel<<<nX / 1024, 256, 0, stream>>>(x, xb, nX);
    cast4_kernel<<<dim3(1024, 4), 256, 0, stream>>>(
        wq, wk, wv, wo,
        wqkvb, wqkvb + 1024 * 1024, wqkvb + 2 * 1024 * 1024, wob);

    gemm_qkv_8ph<<<dim3(32, 12), 512, 0, stream>>>(xb, wqkvb, bq, bk, bv,
                                                   Qb, Kb, VTb);

    flash_attn<<<dim3(SEQ / 256, NH, BSZ), 512, 0, stream>>>(Qb, Kb, VTb, xb);

    gemm_bt<0><<<dim3(64, 8), 256, 0, stream>>>(xb, wob, bo,
                                                d_out, (int)M, EMB, EMB);
}

// Round 16
// 199.501 us; speedup vs baseline: 1.0832x; 1.0832x over previous
//
#include <hip/hip_runtime.h>
#include <stdint.h>

#define SEQ 2048
#define BSZ 4
#define NH 16
#define HD 64
#define EMB 1024
#define NT (SEQ / 64)
#define QSCALE 0.1803368801111f   // 0.125 * log2(e)

using bf16x8 = __attribute__((ext_vector_type(8))) __bf16;
using u16x8  = __attribute__((ext_vector_type(8))) unsigned short;
using u32x4  = __attribute__((ext_vector_type(4))) uint32_t;
using f32x4  = __attribute__((ext_vector_type(4))) float;
using f32x16 = __attribute__((ext_vector_type(16))) float;

__device__ __forceinline__ float exp2v(float x) { return __builtin_amdgcn_exp2f(x); }

__device__ __forceinline__ unsigned short f2bf(float f) {
    union { float f; uint32_t u; } v; v.f = f;
    uint32_t r = v.u + 0x7fffu + ((v.u >> 16) & 1u);
    return (unsigned short)(r >> 16);
}

__device__ __forceinline__ uint32_t cvtpk(float lo, float hi) {
    uint32_t r;
    asm("v_cvt_pk_bf16_f32 %0, %1, %2" : "=v"(r) : "v"(lo), "v"(hi));
    return r;
}
__device__ __forceinline__ void plswap(uint32_t& a, uint32_t& b) {
    asm volatile("v_permlane32_swap_b32 %0, %1" : "+v"(a), "+v"(b));
}

// async global->LDS, 16B per lane; dest = wave-uniform base + lane*16
__device__ __forceinline__ void gload16(void* lds, const void* g) {
    __builtin_amdgcn_global_load_lds(
        (const __attribute__((address_space(1))) void*)g,
        (__attribute__((address_space(3))) void*)lds, 16, 0, 0);
}

// ---------------- fused cast fp32 -> bf16: x (8M elems) + 4 weights (1M) ---
// grid: 12288 blocks x 256 threads x 4 elems.
// blocks 0..8191 -> x; then 1024-block segments for wq, wk, wv, wo.
__global__ void cast_all_kernel(const float* __restrict__ x,
                                const float* __restrict__ w0, const float* __restrict__ w1,
                                const float* __restrict__ w2, const float* __restrict__ w3,
                                unsigned short* __restrict__ dx,
                                unsigned short* __restrict__ d0, unsigned short* __restrict__ d1,
                                unsigned short* __restrict__ d2, unsigned short* __restrict__ d3) {
    int bid = blockIdx.x;
    const float* s; unsigned short* d; int base;
    if (bid < 8192)       { s = x;  d = dx; base = bid; }
    else if (bid < 9216)  { s = w0; d = d0; base = bid - 8192; }
    else if (bid < 10240) { s = w1; d = d1; base = bid - 9216; }
    else if (bid < 11264) { s = w2; d = d2; base = bid - 10240; }
    else                  { s = w3; d = d3; base = bid - 11264; }
    int i = (base * 256 + threadIdx.x) * 4;
    float4 v = *(const float4*)(s + i);
    ushort4 o;
    o.x = f2bf(v.x); o.y = f2bf(v.y); o.z = f2bf(v.z); o.w = f2bf(v.w);
    *(ushort4*)(d + i) = o;
}

// ---------------- GEMM (m97 structure, round-10/13 proven) -----------------
// MODE 0: f32 out to C0 (bias b0).  MODE 2: QKV fused — n-seg 0 -> Q (scaled
// by QSCALE), 1 -> K, 2 -> V^T (transposed write [b,h,d,seq]).
template <int MODE>
__global__ __launch_bounds__(256, 2)
void gemm_bt(const unsigned short* __restrict__ A,
             const unsigned short* __restrict__ Bw,
             const float* __restrict__ b0, const float* __restrict__ b1,
             const float* __restrict__ b2,
             void* __restrict__ C0, void* __restrict__ C1, void* __restrict__ C2,
             int M, int N, int Kd) {
    __shared__ unsigned short As[128][64];
    __shared__ unsigned short Bs[128][64];

    const int t    = threadIdx.x;
    const int lane = t & 63;
    const int wid  = t >> 6;
    const int g    = lane >> 4;
    const int lr   = lane & 15;
    const int wm   = wid >> 1, wn = wid & 1;
    const int m0   = blockIdx.x * 128, n0 = blockIdx.y * 128;
    const int srow = lane >> 3;          // 0..7 within 8-row stripe
    const int scol = (lane & 7) * 8;     // shorts

    f32x4 acc[4][4];
    const f32x4 zero = {0.f, 0.f, 0.f, 0.f};
#pragma unroll
    for (int i = 0; i < 4; ++i)
#pragma unroll
        for (int j = 0; j < 4; ++j) acc[i][j] = zero;

    for (int kt = 0; kt < Kd; kt += 64) {
#pragma unroll
        for (int p = 0; p < 4; ++p) {
            int rowA = wid * 32 + p * 8;
            gload16(&As[rowA][0], A  + (size_t)(m0 + rowA + srow) * Kd + kt + scol);
            gload16(&Bs[rowA][0], Bw + (size_t)(n0 + rowA + srow) * Kd + kt + scol);
        }
        __syncthreads();   // compiler drains vmcnt before barrier
#pragma unroll
        for (int ks = 0; ks < 2; ++ks) {
            bf16x8 af[4], bfr[4];
#pragma unroll
            for (int m = 0; m < 4; ++m)
                af[m] = *(const bf16x8*)&As[wm * 64 + m * 16 + lr][ks * 32 + g * 8];
#pragma unroll
            for (int n = 0; n < 4; ++n)
                bfr[n] = *(const bf16x8*)&Bs[wn * 64 + n * 16 + lr][ks * 32 + g * 8];
#pragma unroll
            for (int m = 0; m < 4; ++m)
#pragma unroll
                for (int n = 0; n < 4; ++n)
                    acc[m][n] = __builtin_amdgcn_mfma_f32_16x16x32_bf16(af[m], bfr[n], acc[m][n], 0, 0, 0);
        }
        __syncthreads();
    }

    int seg = MODE == 2 ? (n0 >> 10) : 0;
    if (MODE == 2 && seg == 2) {
        // V^T write: [b*1024 + colL][seq], 4 consecutive seq per ushort4
        unsigned short* CwT = (unsigned short*)C2;
        int nl = n0 & 1023;
#pragma unroll
        for (int n = 0; n < 4; ++n) {
            int colL = nl + wn * 64 + n * 16 + lr;
            float bv = b2[colL];
#pragma unroll
            for (int m = 0; m < 4; ++m) {
                int rowg = m0 + wm * 64 + m * 16 + g * 4;
                int bb = rowg >> 11, seq = rowg & 2047;
                ushort4 w;
                w.x = f2bf(acc[m][n][0] + bv);
                w.y = f2bf(acc[m][n][1] + bv);
                w.z = f2bf(acc[m][n][2] + bv);
                w.w = f2bf(acc[m][n][3] + bv);
                *(ushort4*)(CwT + ((size_t)(bb * 1024 + colL)) * SEQ + seq) = w;
            }
        }
        return;
    }

    const float* bias;
    unsigned short* Cw = nullptr;
    float* Cf = nullptr;
    float scl = 1.0f;
    int nl;
    if (MODE == 2) {
        bias = seg == 0 ? b0 : b1;
        Cw = (unsigned short*)(seg == 0 ? C0 : C1);
        scl = seg == 0 ? QSCALE : 1.0f;
        nl = n0 & 1023;
    } else {
        bias = b0; Cf = (float*)C0; nl = n0;
    }
#pragma unroll
    for (int n = 0; n < 4; ++n) {
        int colL = nl + wn * 64 + n * 16 + lr;
        float bv = bias[colL];
#pragma unroll
        for (int m = 0; m < 4; ++m) {
            int rowg = m0 + wm * 64 + m * 16 + g * 4;
#pragma unroll
            for (int r = 0; r < 4; ++r) {
                float val = (acc[m][n][r] + bv) * scl;
                if (MODE == 2)
                    Cw[(size_t)(rowg + r) * EMB + colL] = f2bf(val);
                else
                    Cf[(size_t)(rowg + r) * EMB + colL] = val;
            }
        }
    }
}

// ---------------- Flash attention v8 (round-8 proven, best: 94.2 us) -------
// Q pre-scaled by 0.125*log2e -> scores are base-2 logits. V comes in as V^T.
// grid: 512 blocks (XCD-swizzled); block 512 = 8 waves; wave = 32 q-rows.
__global__ __launch_bounds__(512, 4)
void flash_attn(const unsigned short* __restrict__ Q,
                const unsigned short* __restrict__ K,
                const unsigned short* __restrict__ VT,
                unsigned short* __restrict__ O) {
    __shared__ unsigned char KsB[2][64 * 128];   // K[k][d],  XOR-16B swizzled
    __shared__ unsigned char VtB[2][64 * 128];   // V^T[d][k], XOR-16B swizzled

    const int nwg  = gridDim.x * gridDim.y * gridDim.z;
    const int cpx  = nwg >> 3;
    const int bid0 = (blockIdx.z * gridDim.y + blockIdx.y) * gridDim.x + blockIdx.x;
    const int bid  = (bid0 % 8) * cpx + (bid0 / 8);
    const int bx   = bid & (gridDim.x - 1);          // SEQ/256 = 8 (pow2)
    const int h    = (bid >> 3) & 15;
    const int b    = bid >> 7;

    const int t    = threadIdx.x;
    const int wid  = t >> 6;
    const int lane = t & 63;
    const int l31  = lane & 31;
    const int hi   = lane >> 5;
    const int hi16 = hi << 4;
    const int sw   = (l31 & 7) << 4;
    const int qbase = bx * 256 + wid * 32;
    const size_t rowbase = (size_t)b * SEQ;
    const unsigned short* Kh  = K + rowbase * EMB + h * HD;
    const unsigned short* Vth = VT + (size_t)(b * 1024 + h * HD) * SEQ;

    const int grow = t >> 3;                         // K row / V^T d-row
    const int gc16 = (t & 7) ^ (grow & 7);           // XOR moved to source
    const unsigned short* Ksrc0 = Kh  + (size_t)grow * EMB + gc16 * 8;
    const unsigned short* Vsrc0 = Vth + (size_t)grow * SEQ + gc16 * 8;

    bf16x8 qf[4];
#pragma unroll
    for (int db = 0; db < 4; ++db)
        qf[db] = *(const bf16x8*)(Q + (rowbase + qbase + l31) * EMB + h * HD + db * 16 + hi * 8);

    // all-ones B fragment: P x ones MFMA = softmax denominator in C-layout
    bf16x8 vones;
#pragma unroll
    for (int j = 0; j < 8; ++j) vones[j] = (__bf16)1.0f;

    f32x16 o0, o1, o2;
#pragma unroll
    for (int r = 0; r < 16; ++r) { o0[r] = 0.f; o1[r] = 0.f; o2[r] = 0.f; }
    float me = -1e30f;

    auto issue_tile = [&](int kt) {
        unsigned char* Ks = KsB[kt & 1] + wid * 1024;   // wave-uniform base
        unsigned char* Vt = VtB[kt & 1] + wid * 1024;
        gload16(Ks, Ksrc0 + (size_t)kt * 64 * EMB);
        gload16(Vt, Vsrc0 + kt * 64);
    };
    issue_tile(0);

    for (int kt = 0; kt < NT; ++kt) {
        unsigned char* Ks = KsB[kt & 1];
        unsigned char* Vt = VtB[kt & 1];

        __syncthreads();                      // drains DMA for tile kt; prev reads done

        if (kt + 1 < NT) issue_tile(kt + 1);  // DMA next tile into other buffer

        // S^T = K * Q^T : lane holds 32 k-scores for q = lane&31 (base-2 logits)
        f32x16 s0, s1;
#pragma unroll
        for (int r = 0; r < 16; ++r) { s0[r] = 0.f; s1[r] = 0.f; }
        __builtin_amdgcn_s_setprio(1);
#pragma unroll
        for (int db = 0; db < 4; ++db) {
            bf16x8 kf0 = *(const bf16x8*)(Ks + l31 * 128        + ((db * 32 + hi16) ^ sw));
            bf16x8 kf1 = *(const bf16x8*)(Ks + (l31 + 32) * 128 + ((db * 32 + hi16) ^ sw));
            s0 = __builtin_amdgcn_mfma_f32_32x32x16_bf16(kf0, qf[db], s0, 0, 0, 0);
            s1 = __builtin_amdgcn_mfma_f32_32x32x16_bf16(kf1, qf[db], s1, 0, 0, 0);
        }
        __builtin_amdgcn_s_setprio(0);

        // row max (max3-friendly nesting)
        float pm = fmaxf(fmaxf(s0[0], s0[1]), s0[2]);
#pragma unroll
        for (int r = 3; r < 15; r += 2) pm = fmaxf(fmaxf(pm, s0[r]), s0[r + 1]);
        pm = fmaxf(pm, s0[15]);
#pragma unroll
        for (int r = 0; r < 16; r += 2) pm = fmaxf(fmaxf(pm, s1[r]), s1[r + 1]);
        pm = fmaxf(pm, __shfl_xor(pm, 32));

        // defer-max: only rescale when max grew by > 8 (P bounded by 2^8)
        if (!__all(pm - me <= 8.0f)) {
            float mn = fmaxf(me, pm);
            float al = exp2v(me - mn);
            me = mn;
#pragma unroll
            for (int r = 0; r < 16; ++r) {
                int addr = hi16 + (((r & 3) + 8 * (r >> 2)) << 2);
                float ar = __int_as_float(
                    __builtin_amdgcn_ds_bpermute(addr, __float_as_int(al)));
                o0[r] *= ar; o1[r] *= ar; o2[r] *= ar;
            }
        }

        // exp2 (packed subtract; row-sum is MFMA'd below)
        s0 = s0 - me;
        s1 = s1 - me;
#pragma unroll
        for (int r = 0; r < 16; ++r) s0[r] = exp2v(s0[r]);
#pragma unroll
        for (int r = 0; r < 16; ++r) s1[r] = exp2v(s1[r]);

        // pack P -> bf16 A-fragments via cvt_pk + permlane32_swap
        bf16x8 pa[4];
#pragma unroll
        for (int kb = 0; kb < 2; ++kb) {
            uint32_t dw[8];
#pragma unroll
            for (int i = 0; i < 8; ++i)
                dw[i] = kb == 0 ? cvtpk(s0[2 * i], s0[2 * i + 1])
                                : cvtpk(s1[2 * i], s1[2 * i + 1]);
            plswap(dw[0], dw[2]); plswap(dw[1], dw[3]);
            plswap(dw[4], dw[6]); plswap(dw[5], dw[7]);
            u32x4 w0 = {dw[0], dw[1], dw[2], dw[3]};
            u32x4 w1 = {dw[4], dw[5], dw[6], dw[7]};
            pa[kb * 2]     = __builtin_bit_cast(bf16x8, w0);
            pa[kb * 2 + 1] = __builtin_bit_cast(bf16x8, w1);
        }

        // PV + row-sum (P x ones)
        __builtin_amdgcn_s_setprio(1);
#pragma unroll
        for (int kk = 0; kk < 4; ++kk) {
            bf16x8 vf0 = *(const bf16x8*)(Vt + l31 * 128        + ((kk * 32 + hi16) ^ sw));
            bf16x8 vf1 = *(const bf16x8*)(Vt + (l31 + 32) * 128 + ((kk * 32 + hi16) ^ sw));
            o0 = __builtin_amdgcn_mfma_f32_32x32x16_bf16(pa[kk], vf0, o0, 0, 0, 0);
            o1 = __builtin_amdgcn_mfma_f32_32x32x16_bf16(pa[kk], vf1, o1, 0, 0, 0);
            o2 = __builtin_amdgcn_mfma_f32_32x32x16_bf16(pa[kk], vones, o2, 0, 0, 0);
        }
        __builtin_amdgcn_s_setprio(0);
    }

    // epilogue: o2[r] holds the softmax denominator for this lane's q-row
#pragma unroll
    for (int r = 0; r < 16; ++r) {
        float inv = 1.0f / o2[r];
        int q = qbase + (r & 3) + 8 * (r >> 2) + 4 * hi;
        size_t ro = (rowbase + q) * EMB + h * HD;
        O[ro + l31]      = f2bf(o0[r] * inv);
        O[ro + 32 + l31] = f2bf(o1[r] * inv);
    }
}

extern "C" void kernel_launch(void* const* d_in, const int* in_sizes, int n_in,
                              void* d_out, int out_size, void* d_ws, size_t ws_size,
                              hipStream_t stream) {
    const float* x  = (const float*)d_in[0];
    const float* wq = (const float*)d_in[1];
    const float* bq = (const float*)d_in[2];
    const float* wk = (const float*)d_in[3];
    const float* bk = (const float*)d_in[4];
    const float* wv = (const float*)d_in[5];
    const float* bv = (const float*)d_in[6];
    const float* wo = (const float*)d_in[7];
    const float* bo = (const float*)d_in[8];

    char* ws = (char*)d_ws;
    const size_t M = (size_t)BSZ * SEQ;              // 8192
    unsigned short* xb    = (unsigned short*)ws;                       // 16 MB, reused as attn out
    unsigned short* wqkvb = (unsigned short*)(ws + (size_t)16 * 1024 * 1024);  // 6 MB
    unsigned short* wob   = (unsigned short*)(ws + (size_t)22 * 1024 * 1024);  // 2 MB
    unsigned short* Qb    = (unsigned short*)(ws + (size_t)24 * 1024 * 1024);
    unsigned short* Kb    = Qb + M * EMB;
    unsigned short* VTb   = Kb + M * EMB;            // V^T [b*16+h][64][2048]

    cast_all_kernel<<<12288, 256, 0, stream>>>(
        x, wq, wk, wv, wo,
        xb, wqkvb, wqkvb + 1024 * 1024, wqkvb + 2 * 1024 * 1024, wob);

    gemm_bt<2><<<dim3(64, 24), 256, 0, stream>>>(xb, wqkvb, bq, bk, bv,
                                                 Qb, Kb, VTb, (int)M, 3 * EMB, EMB);

    flash_attn<<<dim3(SEQ / 256, NH, BSZ), 512, 0, stream>>>(Qb, Kb, VTb, xb);

    gemm_bt<0><<<dim3(64, 8), 256, 0, stream>>>(xb, wob, bo, nullptr, nullptr,
                                                d_out, nullptr, nullptr, (int)M, EMB, EMB);
}